// Round 8
// baseline (131.984 us; speedup 1.0000x reference)
//
#include <hip/hip_runtime.h>
#include <hip/hip_bf16.h>
#include <math.h>

// R8 = R7 + NREP x redundant j-sweeps (atomicMin idempotent -> same output).
// Purpose: measurement. Stage1's inner loop scaled 8x so it appears in the
// rocprof top-5 with full counters; Δtotal/7 = true inner-loop time.

#define B 8
#define N 4096
#define NJ 16
#define NI 2
#define S1B 256
#define TX 8          // S1B*TX*NI = 4096 queries per (dir,n)
#define JC (N / NJ)   // 256 db points per stage1 block
#define NREP 8        // redundant sweeps (idempotent)

// ws layout: mind2[2*B*N] uints (256 KB)

__global__ __launch_bounds__(256) void chamfer_init(unsigned* __restrict__ mind2) {
  mind2[blockIdx.x * 256 + threadIdx.x] = 0x7F800000u;  // +inf
}

__global__ __launch_bounds__(S1B) void chamfer_stage1(
    const float2* __restrict__ P1, const float2* __restrict__ P2,
    unsigned* __restrict__ mind2) {
  __shared__ float4 yb[JC];

  int b = blockIdx.x;
  int c = b & (NJ - 1);
  int itile = (b >> 4) & (NI - 1);
  int n = (b >> 5) & (B - 1);
  int dir = b >> 8;

  const float2* __restrict__ Q = dir ? P2 : P1;  // queries
  const float2* __restrict__ D = dir ? P1 : P2;  // database

  const float2* dbase = D + n * N + c * JC;
  for (int t = threadIdx.x; t < JC; t += S1B) {
    float2 p = dbase[t];
    yb[t] = make_float4(-2.f * p.x, -2.f * p.y,
                        fmaf(p.x, p.x, p.y * p.y), 0.f);
  }
  __syncthreads();

  float qx[TX], qy[TX], qq[TX], m[TX];
  const float2* qbase = Q + n * N + itile * (S1B * TX) + threadIdx.x;
#pragma unroll
  for (int k = 0; k < TX; ++k) {
    float2 q = qbase[k * S1B];
    qx[k] = q.x; qy[k] = q.y;
    qq[k] = fmaf(q.x, q.x, q.y * q.y);
    m[k] = INFINITY;
  }

  for (int rep = 0; rep < NREP; ++rep) {
    // wave-uniform LDS broadcast; 3 VALU slots per pair
#pragma unroll 4
    for (int j = 0; j < JC; ++j) {
      float4 y = yb[j];
#pragma unroll
      for (int k = 0; k < TX; ++k) {
        float t = fmaf(qx[k], y.x, fmaf(qy[k], y.y, y.z));
        m[k] = fminf(m[k], t);
      }
    }
    // keep m[] opaque + clobber memory so each rep fully recomputes
#pragma unroll
    for (int k = 0; k < TX; ++k)
      asm volatile("" : "+v"(m[k]) :: "memory");
  }

  unsigned* __restrict__ dst =
      mind2 + (dir * B + n) * N + itile * (S1B * TX) + threadIdx.x;
#pragma unroll
  for (int k = 0; k < TX; ++k) {
    float d2 = fmaxf(m[k] + qq[k], 0.f);   // true squared distance, >= 0
    atomicMin(dst + k * S1B, __float_as_uint(d2));
  }
}

// grid = B blocks; each reduces both dirs for its n.
__global__ __launch_bounds__(256) void chamfer_stage2(
    const unsigned* __restrict__ mind2, float* __restrict__ out) {
  int n = blockIdx.x;
  float acc = 0.f;
#pragma unroll
  for (int dir = 0; dir < 2; ++dir) {
    const unsigned* __restrict__ p = mind2 + (dir * B + n) * N;
#pragma unroll
    for (int s = 0; s < N / 256; ++s)
      acc += sqrtf(__uint_as_float(p[threadIdx.x + s * 256]));
  }
  __shared__ float red[256];
  red[threadIdx.x] = acc;
  __syncthreads();
  for (int s = 128; s > 0; s >>= 1) {
    if (threadIdx.x < s) red[threadIdx.x] += red[threadIdx.x + s];
    __syncthreads();
  }
  if (threadIdx.x == 0) out[n] = red[0] * (0.5f / (float)N);
}

extern "C" void kernel_launch(void* const* d_in, const int* in_sizes, int n_in,
                              void* d_out, int out_size, void* d_ws, size_t ws_size,
                              hipStream_t stream) {
  const float2* P1 = (const float2*)d_in[0];
  const float2* P2 = (const float2*)d_in[1];
  float* out = (float*)d_out;
  unsigned* mind2 = (unsigned*)d_ws;

  chamfer_init<<<dim3(2 * B * N / 256), 256, 0, stream>>>(mind2);
  chamfer_stage1<<<dim3(2 * B * NI * NJ), S1B, 0, stream>>>(P1, P2, mind2);
  chamfer_stage2<<<dim3(B), 256, 0, stream>>>(mind2, out);
}

// Round 9
// 31.697 us; speedup vs baseline: 4.1639x; 4.1639x over previous
//
#include <hip/hip_runtime.h>
#include <hip/hip_bf16.h>
#include <math.h>

// Chamfer 2D, B=8, N=4096, fp32 — atomicMin formulation.
// R9 = R7 + (a) v_min3_f32 j-pairing in stage1 (2.5 VALU slots/pair),
//          (b) stage2 parallelized to 64 blocks with fused last-arrival tail.
// mind2[dir][n][i] holds uint bits of d^2>=0 (float order == uint order,
// so atomicMin is an exact order-independent min -> deterministic).

#define B 8
#define N 4096
#define NJ 16
#define NI 2
#define S1B 256
#define TX 8          // S1B*TX*NI = 4096 queries per (dir,n)
#define JC (N / NJ)   // 256 db points per stage1 block

// ws layout: mind2[2*B*N] uints (256 KB) | bs[64] floats | cnt[8] uints

typedef unsigned uint4v __attribute__((ext_vector_type(4)));

__global__ __launch_bounds__(256) void chamfer_init(unsigned* __restrict__ mind2,
                                                    unsigned* __restrict__ cnt) {
  uint4v v = {0x7F800000u, 0x7F800000u, 0x7F800000u, 0x7F800000u};
  ((uint4v*)mind2)[blockIdx.x * 256 + threadIdx.x] = v;
  if (blockIdx.x == 0 && threadIdx.x < B) cnt[threadIdx.x] = 0u;
}

__global__ __launch_bounds__(S1B) void chamfer_stage1(
    const float2* __restrict__ P1, const float2* __restrict__ P2,
    unsigned* __restrict__ mind2) {
  __shared__ float4 yb[JC];

  int b = blockIdx.x;
  int c = b & (NJ - 1);
  int itile = (b >> 4) & (NI - 1);
  int n = (b >> 5) & (B - 1);
  int dir = b >> 8;

  const float2* __restrict__ Q = dir ? P2 : P1;  // queries
  const float2* __restrict__ D = dir ? P1 : P2;  // database

  const float2* dbase = D + n * N + c * JC;
  for (int t = threadIdx.x; t < JC; t += S1B) {
    float2 p = dbase[t];
    yb[t] = make_float4(-2.f * p.x, -2.f * p.y,
                        fmaf(p.x, p.x, p.y * p.y), 0.f);
  }
  __syncthreads();

  float qx[TX], qy[TX], qq[TX], m[TX];
  const float2* qbase = Q + n * N + itile * (S1B * TX) + threadIdx.x;
#pragma unroll
  for (int k = 0; k < TX; ++k) {
    float2 q = qbase[k * S1B];
    qx[k] = q.x; qy[k] = q.y;
    qq[k] = fmaf(q.x, q.x, q.y * q.y);
    m[k] = INFINITY;
  }

  // 2 j's per iter: 4 fma + 1 v_min3 per query => 2.5 VALU slots/pair
#pragma unroll 2
  for (int jp = 0; jp < JC; jp += 2) {
    float4 y0 = yb[jp];
    float4 y1 = yb[jp + 1];
#pragma unroll
    for (int k = 0; k < TX; ++k) {
      float t0 = fmaf(qx[k], y0.x, fmaf(qy[k], y0.y, y0.z));
      float t1 = fmaf(qx[k], y1.x, fmaf(qy[k], y1.y, y1.z));
      asm("v_min3_f32 %0, %0, %1, %2" : "+v"(m[k]) : "v"(t0), "v"(t1));
    }
  }

  unsigned* __restrict__ dst =
      mind2 + (dir * B + n) * N + itile * (S1B * TX) + threadIdx.x;
#pragma unroll
  for (int k = 0; k < TX; ++k) {
    float d2 = fmaxf(m[k] + qq[k], 0.f);   // true squared distance, >= 0
    atomicMin(dst + k * S1B, __float_as_uint(d2));
  }
}

// grid = 64 blocks (8 per n); last arrival per n writes out[n].
__global__ __launch_bounds__(256) void chamfer_stage2(
    const unsigned* __restrict__ mind2, float* __restrict__ bs,
    unsigned* __restrict__ cnt, float* __restrict__ out) {
  int bid = blockIdx.x;
  int n = bid >> 3, g = bid & 7;
  int i = g * 512 + threadIdx.x;

  float acc =
      sqrtf(__uint_as_float(mind2[(0 * B + n) * N + i])) +
      sqrtf(__uint_as_float(mind2[(0 * B + n) * N + i + 256])) +
      sqrtf(__uint_as_float(mind2[(1 * B + n) * N + i])) +
      sqrtf(__uint_as_float(mind2[(1 * B + n) * N + i + 256]));

  __shared__ float red[256];
  red[threadIdx.x] = acc;
  __syncthreads();
  for (int s = 128; s > 0; s >>= 1) {
    if (threadIdx.x < s) red[threadIdx.x] += red[threadIdx.x + s];
    __syncthreads();
  }

  if (threadIdx.x == 0) {
    bs[bid] = red[0];
    __threadfence();                       // release bs[bid]
    unsigned old = atomicAdd(&cnt[n], 1u); // device scope
    if (old == 7u) {
      __threadfence();                     // acquire
      float v = 0.f;
#pragma unroll
      for (int gg = 0; gg < 8; ++gg)       // fixed order -> deterministic
        v += __uint_as_float(__hip_atomic_load(
            (const unsigned*)&bs[n * 8 + gg],
            __ATOMIC_RELAXED, __HIP_MEMORY_SCOPE_AGENT));
      out[n] = v * (0.5f / (float)N);
    }
  }
}

extern "C" void kernel_launch(void* const* d_in, const int* in_sizes, int n_in,
                              void* d_out, int out_size, void* d_ws, size_t ws_size,
                              hipStream_t stream) {
  const float2* P1 = (const float2*)d_in[0];
  const float2* P2 = (const float2*)d_in[1];
  float* out = (float*)d_out;

  unsigned* mind2 = (unsigned*)d_ws;
  float* bs = (float*)(mind2 + 2 * B * N);
  unsigned* cnt = (unsigned*)(bs + 64);

  chamfer_init<<<dim3(2 * B * N / 1024), 256, 0, stream>>>(mind2, cnt);
  chamfer_stage1<<<dim3(2 * B * NI * NJ), S1B, 0, stream>>>(P1, P2, mind2);
  chamfer_stage2<<<dim3(64), 256, 0, stream>>>(mind2, bs, cnt, out);
}

// Round 10
// 31.212 us; speedup vs baseline: 4.2286x; 1.0155x over previous
//
#include <hip/hip_runtime.h>
#include <hip/hip_bf16.h>
#include <math.h>

// Chamfer 2D, B=8, N=4096, fp32 — atomicMin formulation.
// R10 = R7 with TX=16/NI=1/NJ=32: shifts per-j pipe balance from LDS:VALU
// 96:96 (co-limited, R9 showed min3 invisible) to 96:160 (VALU-bound),
// so min3's 2.5 slots/pair sets the floor (~8.5 us ideal for 268M pairs).
// mind2[dir][n][i] = uint bits of d^2>=0; atomicMin exact & order-independent.

#define B 8
#define N 4096
#define NJ 32
#define S1B 256
#define TX 16         // S1B*TX = 4096 queries per (dir,n), NI=1
#define JC (N / NJ)   // 128 db points per stage1 block

// ws layout: mind2[2*B*N] uints (256 KB)

typedef unsigned uint4v __attribute__((ext_vector_type(4)));

__global__ __launch_bounds__(256) void chamfer_init(unsigned* __restrict__ mind2) {
  uint4v v = {0x7F800000u, 0x7F800000u, 0x7F800000u, 0x7F800000u};
  ((uint4v*)mind2)[blockIdx.x * 256 + threadIdx.x] = v;
}

__global__ __launch_bounds__(S1B) void chamfer_stage1(
    const float2* __restrict__ P1, const float2* __restrict__ P2,
    unsigned* __restrict__ mind2) {
  __shared__ float4 yb[JC];

  int b = blockIdx.x;
  int c = b & (NJ - 1);
  int n = (b >> 5) & (B - 1);
  int dir = b >> 8;

  const float2* __restrict__ Q = dir ? P2 : P1;  // queries
  const float2* __restrict__ D = dir ? P1 : P2;  // database

  const float2* dbase = D + n * N + c * JC;
  if (threadIdx.x < JC) {
    float2 p = dbase[threadIdx.x];
    yb[threadIdx.x] = make_float4(-2.f * p.x, -2.f * p.y,
                                  fmaf(p.x, p.x, p.y * p.y), 0.f);
  }
  __syncthreads();

  float qx[TX], qy[TX], qq[TX], m[TX];
  const float2* qbase = Q + n * N + threadIdx.x;
#pragma unroll
  for (int k = 0; k < TX; ++k) {
    float2 q = qbase[k * S1B];
    qx[k] = q.x; qy[k] = q.y;
    qq[k] = fmaf(q.x, q.x, q.y * q.y);
    m[k] = INFINITY;
  }

  // 2 j's per iter: 4 fma + 1 min3 per query => 2.5 VALU slots per pair
#pragma unroll 2
  for (int jp = 0; jp < JC; jp += 2) {
    float4 y0 = yb[jp];
    float4 y1 = yb[jp + 1];
#pragma unroll
    for (int k = 0; k < TX; ++k) {
      float t0 = fmaf(qx[k], y0.x, fmaf(qy[k], y0.y, y0.z));
      float t1 = fmaf(qx[k], y1.x, fmaf(qy[k], y1.y, y1.z));
      m[k] = fminf(fminf(m[k], t0), t1);   // fuses to v_min3_f32
    }
  }

  unsigned* __restrict__ dst = mind2 + (dir * B + n) * N + threadIdx.x;
#pragma unroll
  for (int k = 0; k < TX; ++k) {
    float d2 = fmaxf(m[k] + qq[k], 0.f);   // true squared distance, >= 0
    atomicMin(dst + k * S1B, __float_as_uint(d2));
  }
}

// grid = B blocks; each reduces both dirs for its n.
__global__ __launch_bounds__(256) void chamfer_stage2(
    const unsigned* __restrict__ mind2, float* __restrict__ out) {
  int n = blockIdx.x;
  float acc = 0.f;
#pragma unroll
  for (int dir = 0; dir < 2; ++dir) {
    const unsigned* __restrict__ p = mind2 + (dir * B + n) * N;
#pragma unroll
    for (int s = 0; s < N / 256; ++s)
      acc += sqrtf(__uint_as_float(p[threadIdx.x + s * 256]));
  }
  __shared__ float red[256];
  red[threadIdx.x] = acc;
  __syncthreads();
  for (int s = 128; s > 0; s >>= 1) {
    if (threadIdx.x < s) red[threadIdx.x] += red[threadIdx.x + s];
    __syncthreads();
  }
  if (threadIdx.x == 0) out[n] = red[0] * (0.5f / (float)N);
}

extern "C" void kernel_launch(void* const* d_in, const int* in_sizes, int n_in,
                              void* d_out, int out_size, void* d_ws, size_t ws_size,
                              hipStream_t stream) {
  const float2* P1 = (const float2*)d_in[0];
  const float2* P2 = (const float2*)d_in[1];
  float* out = (float*)d_out;
  unsigned* mind2 = (unsigned*)d_ws;

  chamfer_init<<<dim3(2 * B * N / 1024), 256, 0, stream>>>(mind2);
  chamfer_stage1<<<dim3(2 * B * NJ), S1B, 0, stream>>>(P1, P2, mind2);
  chamfer_stage2<<<dim3(B), 256, 0, stream>>>(mind2, out);
}